// Round 9
// baseline (94.052 us; speedup 1.0000x reference)
//
#include <hip/hip_runtime.h>
#include <hip/hip_bf16.h>

#define BB 4
#define TT 2048
#define CC 1024
#define HH 64
#define LOG2E 1.4426950408889634f
#define QSCALE (0.125f * LOG2E)

typedef __attribute__((ext_vector_type(8))) unsigned short ushort8;
typedef __attribute__((ext_vector_type(4))) unsigned short ushort4v;
typedef __attribute__((ext_vector_type(8))) __bf16 bf16x8;
typedef __attribute__((ext_vector_type(4))) float float4v;

static __device__ __forceinline__ unsigned short f2bf(float f) {
    return __builtin_bit_cast(unsigned short, (__bf16)f);  // RNE, hw cvt
}

static __device__ __forceinline__ float4v mfma16(ushort8 a, ushort8 b, float4v c) {
    return __builtin_amdgcn_mfma_f32_16x16x32_bf16(
        __builtin_bit_cast(bf16x8, a), __builtin_bit_cast(bf16x8, b), c, 0, 0, 0);
}

static __device__ __forceinline__ ushort8 cvt8(float4v a, float4v b) {
    ushort8 r;
#pragma unroll
    for (int i = 0; i < 4; ++i) { r[i] = f2bf(a[i]); r[4 + i] = f2bf(b[i]); }
    return r;
}

// raw barrier: publish LDS writes (lgkmcnt) WITHOUT draining vmcnt.
#define BARRIER()                                            \
    do {                                                     \
        asm volatile("s_waitcnt lgkmcnt(0)" ::: "memory");   \
        __builtin_amdgcn_s_barrier();                        \
        asm volatile("" ::: "memory");                       \
    } while (0)

// ---------------------------------------------------------------------------
// Kernel 0: pack W (f32 [C][64] x3) into MFMA-B-fragment-interleaved bf16.
// unit U = ((kc*2 + ks)*12 + nt)*64 + lane, 8 bf16/unit. QSCALE folded in Wq.
// ---------------------------------------------------------------------------
__global__ __launch_bounds__(256) void wconv_kernel(
    const float* __restrict__ Wq, const float* __restrict__ Wk,
    const float* __restrict__ Wv, unsigned short* __restrict__ wf)
{
    __shared__ __align__(16) float wsT[3][64][68];   // transposed, pad 64->68
    const int kc = blockIdx.x / 6, part = blockIdx.x % 6;
    const int t = threadIdx.x;
    const int r = t >> 2, c0 = (t & 3) << 4;
    const float* Ws[3] = {Wq, Wk, Wv};
#pragma unroll
    for (int y = 0; y < 3; ++y) {
        const float* src = Ws[y] + (size_t)(kc * 64 + r) * HH + c0;
        const float sc = (y == 0) ? QSCALE : 1.0f;
#pragma unroll
        for (int i = 0; i < 16; ++i) wsT[y][c0 + i][r] = src[i] * sc;
    }
    __syncthreads();
    const int U = part * 256 + t;
    const int lane = U & 63, qq = U >> 6;
    const int nt = qq % 12, ks = qq / 12;
    const int y = nt >> 2;
    const int col = 16 * (nt & 3) + (lane & 15);
    const int kl = ks * 32 + 8 * (lane >> 4);
    float4v v0 = *(const float4v*)&wsT[y][col][kl];
    float4v v1 = *(const float4v*)&wsT[y][col][kl + 4];
    *(ushort8*)&wf[((size_t)kc * 1536 + U) * 8] = cvt8(v0, v1);
}

// ---------------------------------------------------------------------------
// Kernel 1: fused q/k/v projection, BM=64. 128 blocks x 8 waves.
// Wave = (m-half mh, n-group ng of 3 tiles). W traffic 196->49 MB: the two
// m-half waves of an n-group read identical W addresses (L1 dedup).
// x staged via 4-deep register pipeline into swizzled LDS (8KB dbuf);
// W streamed 2-deep; raw barriers; 12 MFMA/wave/step. v tiles swap operands.
// ---------------------------------------------------------------------------
__global__ __launch_bounds__(512, 2) void proj_kernel(
    const float* __restrict__ x, const unsigned short* __restrict__ wf,
    unsigned short* __restrict__ qo, unsigned short* __restrict__ ko,
    unsigned short* __restrict__ vo)
{
    __shared__ __align__(16) unsigned short xa[2][4096];   // 2 x 8KB

    const int t0 = blockIdx.x << 6;                        // 64 rows
    const int tid = threadIdx.x;
    const int w = tid >> 6;
    const int lane = tid & 63;
    const int l15 = lane & 15, g = lane >> 4;
    const int mh = w & 1, ng = w >> 1;
    const int nt0 = 3 * ng;

    // x staging: 512 thr, one swizzled 16B unit each (64 rows x 8 units)
    const int sr = tid >> 3, su = tid & 7;
    const int soff = (sr * 8 + (su ^ (sr & 7))) * 8;
    const float* xp = x + (size_t)(t0 + sr) * CC + su * 8;

    float4v xr[4][2];                                      // 4-deep x pipeline
#pragma unroll
    for (int p = 0; p < 4; ++p) {
        xr[p][0] = *(const float4v*)(xp + p * 64);
        xr[p][1] = *(const float4v*)(xp + p * 64 + 4);
    }

    // W stream: slot s = kc*2+ks at +s*6144 ushorts
    const unsigned short* wpj[3];
#pragma unroll
    for (int jj = 0; jj < 3; ++jj)
        wpj[jj] = wf + ((size_t)(nt0 + jj) * 64 + lane) * 8;
    ushort8 bc[3][2], bn[3][2];
#pragma unroll
    for (int jj = 0; jj < 3; ++jj)
#pragma unroll
        for (int ks = 0; ks < 2; ++ks) {
            bc[jj][ks] = *(const ushort8*)(wpj[jj] + (size_t)ks * 6144);
            bn[jj][ks] = *(const ushort8*)(wpj[jj] + (size_t)(2 + ks) * 6144);
        }

    *(ushort8*)&xa[0][soff] = cvt8(xr[0][0], xr[0][1]);
    BARRIER();

    const int row0 = 32 * mh + l15, row1 = row0 + 16;
    const int a00 = (row0 * 8 + (g ^ (row0 & 7))) * 8;
    const int a01 = (row0 * 8 + ((4 + g) ^ (row0 & 7))) * 8;
    const int a10 = (row1 * 8 + (g ^ (row1 & 7))) * 8;
    const int a11 = (row1 * 8 + ((4 + g) ^ (row1 & 7))) * 8;

    float4v acc[2][3];
#pragma unroll
    for (int mt = 0; mt < 2; ++mt)
#pragma unroll
        for (int jj = 0; jj < 3; ++jj) acc[mt][jj] = (float4v)0.0f;

    const bool isv = nt0 + 2 >= 8 && nt0 >= 8;   // ng==3 all-v; ng==2 mixed
#pragma unroll
    for (int kc = 0; kc < 16; ++kc) {
        const int cur = kc & 1;
        if (kc + 4 < 16) {
            xr[kc & 3][0] = *(const float4v*)(xp + (kc + 4) * 64);
            xr[kc & 3][1] = *(const float4v*)(xp + (kc + 4) * 64 + 4);
        }
        ushort8 nw[3][2];
        if (kc + 2 < 16) {
#pragma unroll
            for (int jj = 0; jj < 3; ++jj)
#pragma unroll
                for (int ks = 0; ks < 2; ++ks)
                    nw[jj][ks] = *(const ushort8*)
                        (wpj[jj] + (size_t)(2 * kc + 4 + ks) * 6144);
        }
        ushort8 af00 = *(const ushort8*)&xa[cur][a00];
        ushort8 af01 = *(const ushort8*)&xa[cur][a01];
        ushort8 af10 = *(const ushort8*)&xa[cur][a10];
        ushort8 af11 = *(const ushort8*)&xa[cur][a11];
#pragma unroll
        for (int jj = 0; jj < 3; ++jj) {
            if (nt0 + jj < 8) {           // q,k: D = x*W
                acc[0][jj] = mfma16(af00, bc[jj][0], acc[0][jj]);
                acc[0][jj] = mfma16(af01, bc[jj][1], acc[0][jj]);
                acc[1][jj] = mfma16(af10, bc[jj][0], acc[1][jj]);
                acc[1][jj] = mfma16(af11, bc[jj][1], acc[1][jj]);
            } else {                      // v: D = (x*W)^T
                acc[0][jj] = mfma16(bc[jj][0], af00, acc[0][jj]);
                acc[0][jj] = mfma16(bc[jj][1], af01, acc[0][jj]);
                acc[1][jj] = mfma16(bc[jj][0], af10, acc[1][jj]);
                acc[1][jj] = mfma16(bc[jj][1], af11, acc[1][jj]);
            }
        }
        if (kc + 1 < 16)
            *(ushort8*)&xa[cur ^ 1][soff] =
                cvt8(xr[(kc + 1) & 3][0], xr[(kc + 1) & 3][1]);
        BARRIER();
#pragma unroll
        for (int jj = 0; jj < 3; ++jj)
#pragma unroll
            for (int ks = 0; ks < 2; ++ks) {
                bc[jj][ks] = bn[jj][ks];
                if (kc + 2 < 16) bn[jj][ks] = nw[jj][ks];
            }
    }
    (void)isv;

    const int bb = t0 >> 11, tloc = t0 & (TT - 1);
#pragma unroll
    for (int jj = 0; jj < 3; ++jj) {
        const int nt = nt0 + jj;
#pragma unroll
        for (int mt = 0; mt < 2; ++mt) {
            float4v a = acc[mt][jj];
            if (nt < 4) {
#pragma unroll
                for (int r = 0; r < 4; ++r)
                    qo[(size_t)(t0 + 32 * mh + 16 * mt + 4 * g + r) * HH +
                       16 * nt + l15] = f2bf(a[r]);
            } else if (nt < 8) {
#pragma unroll
                for (int r = 0; r < 4; ++r)
                    ko[(size_t)(t0 + 32 * mh + 16 * mt + 4 * g + r) * HH +
                       16 * (nt - 4) + l15] = f2bf(a[r]);
            } else {
#pragma unroll
                for (int r = 0; r < 4; ++r)
                    vo[((size_t)bb * HH + 16 * (nt - 8) + 4 * g + r) * TT +
                       tloc + 32 * mh + 16 * mt + l15] = f2bf(a[r]);
            }
        }
    }
}

// ---------------------------------------------------------------------------
// Kernel 2a: attention partials (flash-decoding). 320 blocks x 4 waves.
// Block = (batch, q-tile j of 64 rows, KV-segment of <=512 keys); wave w owns
// q-rows [64j+16w, +16) independently (no merge in-block). All 4 waves read
// the SAME K/V chunk addresses (L1 dedup -> 1x L2 traffic). K shadow-prefetch.
// Writes per-segment partials (m, l, o) to workspace.
// ---------------------------------------------------------------------------
__global__ __launch_bounds__(256, 2) void attn_partial_kernel(
    const unsigned short* __restrict__ qw,
    const unsigned short* __restrict__ kw,
    const unsigned short* __restrict__ vw,
    float* __restrict__ om_ws, float* __restrict__ ol_ws,
    float* __restrict__ oo_ws)
{
    const int s = blockIdx.x;
    const int b = s & 3;
    const int t = 79 - (s >> 2);                  // heavy segments first
    int j, seg;
    if (t < 8)       { j = t;                   seg = 0; }
    else if (t < 24) { j = 8 + ((t - 8) >> 1);  seg = (t - 8) & 1; }
    else if (t < 48) { j = 16 + (t - 24) / 3;   seg = (t - 24) % 3; }
    else             { j = 24 + ((t - 48) >> 2); seg = (t - 48) & 3; }

    const int tid = threadIdx.x;
    const int w = tid >> 6;
    const int lane = tid & 63;
    const int l15 = lane & 15, g = lane >> 4;
    const int q0w = 64 * j + 16 * w;
    const int q = q0w + l15;

    const unsigned short* qrow = qw + (size_t)(b * TT + q) * HH + 8 * g;
    ushort8 qf0 = *(const ushort8*)qrow;
    ushort8 qf1 = *(const ushort8*)(qrow + 32);

    const unsigned short* kb = kw + (size_t)b * TT * HH;
    const unsigned short* vb = vw + (size_t)b * HH * TT;

    const int kstart = 512 * seg;
    const int kend = min(kstart + 512, 64 * j + 64);
    const int kend_w = min(kend, q0w + 16);       // skip fully-masked chunks

    float m_run = -3.0e38f, l_run = 0.0f;
    float4v o[4];
#pragma unroll
    for (int i = 0; i < 4; ++i) o[i] = (float4v)0.0f;

    ushort8 kl[4], kh[4];
    {
        const unsigned short* kr = kb + (size_t)(kstart + l15) * HH + 8 * g;
#pragma unroll
        for (int f = 0; f < 4; ++f) {
            kl[f] = *(const ushort8*)(kr + f * 16 * HH);
            kh[f] = *(const ushort8*)(kr + f * 16 * HH + 32);
        }
    }

    for (int kv0 = kstart; kv0 < kend_w; kv0 += 64) {
        ushort8 av[4][2];                         // V, issued before softmax
#pragma unroll
        for (int ht = 0; ht < 4; ++ht) {
            const unsigned short* vp =
                vb + (size_t)(16 * ht + l15) * TT + kv0 + 4 * g;
#pragma unroll
            for (int g2 = 0; g2 < 2; ++g2) {
                ushort4v v0 = *(const ushort4v*)(vp + 32 * g2);
                ushort4v v1 = *(const ushort4v*)(vp + 32 * g2 + 16);
#pragma unroll
                for (int r = 0; r < 4; ++r) {
                    av[ht][g2][r] = v0[r];
                    av[ht][g2][4 + r] = v1[r];
                }
            }
        }
        ushort8 nkl[4], nkh[4];                   // K shadow prefetch
        const bool more = kv0 + 64 < kend_w;
        if (more) {
            const unsigned short* kr = kb + (size_t)(kv0 + 64 + l15) * HH + 8 * g;
#pragma unroll
            for (int f = 0; f < 4; ++f) {
                nkl[f] = *(const ushort8*)(kr + f * 16 * HH);
                nkh[f] = *(const ushort8*)(kr + f * 16 * HH + 32);
            }
        }

        float4v sc[4];
#pragma unroll
        for (int f = 0; f < 4; ++f) {
            sc[f] = mfma16(kl[f], qf0, (float4v)0.0f);
            sc[f] = mfma16(kh[f], qf1, sc[f]);
        }

        if (kv0 + 63 > q0w) {                     // causal mask near diagonal
#pragma unroll
            for (int f = 0; f < 4; ++f)
#pragma unroll
                for (int r = 0; r < 4; ++r)
                    if (kv0 + 16 * f + 4 * g + r > q) sc[f][r] = -1e30f;
        }

        float mt = sc[0][0];
#pragma unroll
        for (int f = 0; f < 4; ++f)
#pragma unroll
            for (int r = 0; r < 4; ++r) mt = fmaxf(mt, sc[f][r]);
        mt = fmaxf(mt, __shfl_xor(mt, 16, 64));
        mt = fmaxf(mt, __shfl_xor(mt, 32, 64));

        const float m_new = fmaxf(m_run, mt);
        const float scale = exp2f(m_run - m_new);
        float sum = 0.0f;
#pragma unroll
        for (int f = 0; f < 4; ++f)
#pragma unroll
            for (int r = 0; r < 4; ++r) {
                sc[f][r] = exp2f(sc[f][r] - m_new);
                sum += sc[f][r];
            }
        l_run = l_run * scale + sum;
        m_run = m_new;
#pragma unroll
        for (int i = 0; i < 4; ++i) o[i] *= scale;

        ushort8 bp[2];                            // kappa-packed P
#pragma unroll
        for (int r = 0; r < 4; ++r) {
            bp[0][r] = f2bf(sc[0][r]); bp[0][4 + r] = f2bf(sc[1][r]);
            bp[1][r] = f2bf(sc[2][r]); bp[1][4 + r] = f2bf(sc[3][r]);
        }
#pragma unroll
        for (int ht = 0; ht < 4; ++ht) {
            o[ht] = mfma16(av[ht][0], bp[0], o[ht]);
            o[ht] = mfma16(av[ht][1], bp[1], o[ht]);
        }
        if (more) {
#pragma unroll
            for (int f = 0; f < 4; ++f) { kl[f] = nkl[f]; kh[f] = nkh[f]; }
        }
    }

    l_run += __shfl_xor(l_run, 16, 64);           // finish l across g-groups
    l_run += __shfl_xor(l_run, 32, 64);

    const size_t p = (size_t)(b * 32 + j) * 4 + seg;
    if (lane < 16) {
        om_ws[p * 64 + 16 * w + l15] = m_run;
        ol_ws[p * 64 + 16 * w + l15] = l_run;
    }
#pragma unroll
    for (int ht = 0; ht < 4; ++ht)
        *(float4v*)&oo_ws[(p * 64 + 16 * w + l15) * 64 + 16 * ht + 4 * g] = o[ht];
}

// ---------------------------------------------------------------------------
// Kernel 2b: merge <=4 segment partials per (batch, q-tile). 128 blocks.
// ---------------------------------------------------------------------------
__global__ __launch_bounds__(256) void attn_merge_kernel(
    const float* __restrict__ om_ws, const float* __restrict__ ol_ws,
    const float* __restrict__ oo_ws, float* __restrict__ out)
{
    const int b = blockIdx.x & 3, j = blockIdx.x >> 2;
    const int nseg = (j >> 3) + 1;
    const size_t base = (size_t)(b * 32 + j) * 4;
    const int tid = threadIdx.x;
#pragma unroll 4
    for (int k = 0; k < 16; ++k) {
        const int e = tid + 256 * k;
        const int row = e >> 6, h = e & 63;
        float mstar = -3.0e38f;
        for (int p2 = 0; p2 < nseg; ++p2)
            mstar = fmaxf(mstar, om_ws[(base + p2) * 64 + row]);
        float lsum = 0.0f, osum = 0.0f;
        for (int p2 = 0; p2 < nseg; ++p2) {
            const float al = exp2f(om_ws[(base + p2) * 64 + row] - mstar);
            lsum += al * ol_ws[(base + p2) * 64 + row];
            osum += al * oo_ws[((base + p2) * 64 + row) * 64 + h];
        }
        out[((size_t)b * TT + 64 * j + row) * HH + h] = osum / lsum;
    }
}

extern "C" void kernel_launch(void* const* d_in, const int* in_sizes, int n_in,
                              void* d_out, int out_size, void* d_ws, size_t ws_size,
                              hipStream_t stream) {
    // setup_inputs order: x, Wk, Wq, Wv
    const float* x  = (const float*)d_in[0];
    const float* Wk = (const float*)d_in[1];
    const float* Wq = (const float*)d_in[2];
    const float* Wv = (const float*)d_in[3];

    // ws: q|k|vT bf16 (3 x 1MB) | wf 384KB | om,ol (2 x 128KB f32) | oo 8.4MB
    unsigned short* q_ws  = (unsigned short*)d_ws;
    unsigned short* k_ws  = q_ws + (size_t)BB * TT * HH;
    unsigned short* vt_ws = k_ws + (size_t)BB * TT * HH;
    unsigned short* wf_ws = vt_ws + (size_t)BB * TT * HH;
    float* om_ws = (float*)(wf_ws + 196608);
    float* ol_ws = om_ws + 512 * 64;
    float* oo_ws = ol_ws + 512 * 64;

    wconv_kernel<<<96, 256, 0, stream>>>(Wq, Wk, Wv, wf_ws);
    proj_kernel<<<BB * TT / 64, 512, 0, stream>>>(x, wf_ws, q_ws, k_ws, vt_ws);
    attn_partial_kernel<<<320, 256, 0, stream>>>(q_ws, k_ws, vt_ws,
                                                 om_ws, ol_ws, oo_ws);
    attn_merge_kernel<<<128, 256, 0, stream>>>(om_ws, ol_ws, oo_ws,
                                               (float*)d_out);
}

// Round 10
// 63.489 us; speedup vs baseline: 1.4814x; 1.4814x over previous
//
#include <hip/hip_runtime.h>
#include <hip/hip_bf16.h>

#define BB 4
#define TT 2048
#define CC 1024
#define HH 64
#define LOG2E 1.4426950408889634f
#define QSCALE (0.125f * LOG2E)

typedef __attribute__((ext_vector_type(8))) unsigned short ushort8;
typedef __attribute__((ext_vector_type(4))) unsigned short ushort4v;
typedef __attribute__((ext_vector_type(8))) __bf16 bf16x8;
typedef __attribute__((ext_vector_type(4))) float float4v;

static __device__ __forceinline__ unsigned short f2bf(float f) {
    return __builtin_bit_cast(unsigned short, (__bf16)f);  // RNE, hw cvt
}

static __device__ __forceinline__ float4v mfma16(ushort8 a, ushort8 b, float4v c) {
    return __builtin_amdgcn_mfma_f32_16x16x32_bf16(
        __builtin_bit_cast(bf16x8, a), __builtin_bit_cast(bf16x8, b), c, 0, 0, 0);
}

static __device__ __forceinline__ ushort8 cvt8(float4v a, float4v b) {
    ushort8 r;
#pragma unroll
    for (int i = 0; i < 4; ++i) { r[i] = f2bf(a[i]); r[4 + i] = f2bf(b[i]); }
    return r;
}

#define GLDS16(gp, lp)                                                        \
    __builtin_amdgcn_global_load_lds(                                         \
        (const __attribute__((address_space(1))) unsigned int*)(gp),          \
        (__attribute__((address_space(3))) unsigned int*)(lp), 16, 0, 0)

// raw barrier: publish LDS writes (lgkmcnt) WITHOUT draining vmcnt.
#define BARRIER()                                            \
    do {                                                     \
        asm volatile("s_waitcnt lgkmcnt(0)" ::: "memory");   \
        __builtin_amdgcn_s_barrier();                        \
        asm volatile("" ::: "memory");                       \
    } while (0)

// ---------------------------------------------------------------------------
// Kernel 0: pack W (f32 [C][64] x3) into MFMA-B-fragment-interleaved bf16.
// unit U = ((kc*2 + ks)*12 + nt)*64 + lane, 8 bf16/unit. QSCALE folded in Wq.
// ---------------------------------------------------------------------------
__global__ __launch_bounds__(256) void wconv_kernel(
    const float* __restrict__ Wq, const float* __restrict__ Wk,
    const float* __restrict__ Wv, unsigned short* __restrict__ wf)
{
    __shared__ __align__(16) float wsT[3][64][68];   // transposed, pad 64->68
    const int kc = blockIdx.x / 6, part = blockIdx.x % 6;
    const int t = threadIdx.x;
    const int r = t >> 2, c0 = (t & 3) << 4;
    const float* Ws[3] = {Wq, Wk, Wv};
#pragma unroll
    for (int y = 0; y < 3; ++y) {
        const float* src = Ws[y] + (size_t)(kc * 64 + r) * HH + c0;
        const float sc = (y == 0) ? QSCALE : 1.0f;
#pragma unroll
        for (int i = 0; i < 16; ++i) wsT[y][c0 + i][r] = src[i] * sc;
    }
    __syncthreads();
    const int U = part * 256 + t;
    const int lane = U & 63, qq = U >> 6;
    const int nt = qq % 12, ks = qq / 12;
    const int y = nt >> 2;
    const int col = 16 * (nt & 3) + (lane & 15);
    const int kl = ks * 32 + 8 * (lane >> 4);
    float4v v0 = *(const float4v*)&wsT[y][col][kl];
    float4v v1 = *(const float4v*)&wsT[y][col][kl + 4];
    *(ushort8*)&wf[((size_t)kc * 1536 + U) * 8] = cvt8(v0, v1);
}

// ---------------------------------------------------------------------------
// Kernel 1: fused q/k/v projection, BM=64. 128 blocks x 8 waves. (unchanged)
// ---------------------------------------------------------------------------
__global__ __launch_bounds__(512, 2) void proj_kernel(
    const float* __restrict__ x, const unsigned short* __restrict__ wf,
    unsigned short* __restrict__ qo, unsigned short* __restrict__ ko,
    unsigned short* __restrict__ vo)
{
    __shared__ __align__(16) unsigned short xa[2][4096];   // 2 x 8KB

    const int t0 = blockIdx.x << 6;                        // 64 rows
    const int tid = threadIdx.x;
    const int w = tid >> 6;
    const int lane = tid & 63;
    const int l15 = lane & 15, g = lane >> 4;
    const int mh = w & 1, ng = w >> 1;
    const int nt0 = 3 * ng;

    const int sr = tid >> 3, su = tid & 7;
    const int soff = (sr * 8 + (su ^ (sr & 7))) * 8;
    const float* xp = x + (size_t)(t0 + sr) * CC + su * 8;

    float4v xr[4][2];                                      // 4-deep x pipeline
#pragma unroll
    for (int p = 0; p < 4; ++p) {
        xr[p][0] = *(const float4v*)(xp + p * 64);
        xr[p][1] = *(const float4v*)(xp + p * 64 + 4);
    }

    const unsigned short* wpj[3];
#pragma unroll
    for (int jj = 0; jj < 3; ++jj)
        wpj[jj] = wf + ((size_t)(nt0 + jj) * 64 + lane) * 8;
    ushort8 bc[3][2], bn[3][2];
#pragma unroll
    for (int jj = 0; jj < 3; ++jj)
#pragma unroll
        for (int ks = 0; ks < 2; ++ks) {
            bc[jj][ks] = *(const ushort8*)(wpj[jj] + (size_t)ks * 6144);
            bn[jj][ks] = *(const ushort8*)(wpj[jj] + (size_t)(2 + ks) * 6144);
        }

    *(ushort8*)&xa[0][soff] = cvt8(xr[0][0], xr[0][1]);
    BARRIER();

    const int row0 = 32 * mh + l15, row1 = row0 + 16;
    const int a00 = (row0 * 8 + (g ^ (row0 & 7))) * 8;
    const int a01 = (row0 * 8 + ((4 + g) ^ (row0 & 7))) * 8;
    const int a10 = (row1 * 8 + (g ^ (row1 & 7))) * 8;
    const int a11 = (row1 * 8 + ((4 + g) ^ (row1 & 7))) * 8;

    float4v acc[2][3];
#pragma unroll
    for (int mt = 0; mt < 2; ++mt)
#pragma unroll
        for (int jj = 0; jj < 3; ++jj) acc[mt][jj] = (float4v)0.0f;

#pragma unroll
    for (int kc = 0; kc < 16; ++kc) {
        const int cur = kc & 1;
        if (kc + 4 < 16) {
            xr[kc & 3][0] = *(const float4v*)(xp + (kc + 4) * 64);
            xr[kc & 3][1] = *(const float4v*)(xp + (kc + 4) * 64 + 4);
        }
        ushort8 nw[3][2];
        if (kc + 2 < 16) {
#pragma unroll
            for (int jj = 0; jj < 3; ++jj)
#pragma unroll
                for (int ks = 0; ks < 2; ++ks)
                    nw[jj][ks] = *(const ushort8*)
                        (wpj[jj] + (size_t)(2 * kc + 4 + ks) * 6144);
        }
        ushort8 af00 = *(const ushort8*)&xa[cur][a00];
        ushort8 af01 = *(const ushort8*)&xa[cur][a01];
        ushort8 af10 = *(const ushort8*)&xa[cur][a10];
        ushort8 af11 = *(const ushort8*)&xa[cur][a11];
#pragma unroll
        for (int jj = 0; jj < 3; ++jj) {
            if (nt0 + jj < 8) {           // q,k: D = x*W
                acc[0][jj] = mfma16(af00, bc[jj][0], acc[0][jj]);
                acc[0][jj] = mfma16(af01, bc[jj][1], acc[0][jj]);
                acc[1][jj] = mfma16(af10, bc[jj][0], acc[1][jj]);
                acc[1][jj] = mfma16(af11, bc[jj][1], acc[1][jj]);
            } else {                      // v: D = (x*W)^T
                acc[0][jj] = mfma16(bc[jj][0], af00, acc[0][jj]);
                acc[0][jj] = mfma16(bc[jj][1], af01, acc[0][jj]);
                acc[1][jj] = mfma16(bc[jj][0], af10, acc[1][jj]);
                acc[1][jj] = mfma16(bc[jj][1], af11, acc[1][jj]);
            }
        }
        if (kc + 1 < 16)
            *(ushort8*)&xa[cur ^ 1][soff] =
                cvt8(xr[(kc + 1) & 3][0], xr[(kc + 1) & 3][1]);
        BARRIER();
#pragma unroll
        for (int jj = 0; jj < 3; ++jj)
#pragma unroll
            for (int ks = 0; ks < 2; ++ks) {
                bc[jj][ks] = bn[jj][ks];
                if (kc + 2 < 16) bn[jj][ks] = nw[jj][ks];
            }
    }

    const int bb = t0 >> 11, tloc = t0 & (TT - 1);
#pragma unroll
    for (int jj = 0; jj < 3; ++jj) {
        const int nt = nt0 + jj;
#pragma unroll
        for (int mt = 0; mt < 2; ++mt) {
            float4v a = acc[mt][jj];
            if (nt < 4) {
#pragma unroll
                for (int r = 0; r < 4; ++r)
                    qo[(size_t)(t0 + 32 * mh + 16 * mt + 4 * g + r) * HH +
                       16 * nt + l15] = f2bf(a[r]);
            } else if (nt < 8) {
#pragma unroll
                for (int r = 0; r < 4; ++r)
                    ko[(size_t)(t0 + 32 * mh + 16 * mt + 4 * g + r) * HH +
                       16 * (nt - 4) + l15] = f2bf(a[r]);
            } else {
#pragma unroll
                for (int r = 0; r < 4; ++r)
                    vo[((size_t)bb * HH + 16 * (nt - 8) + 4 * g + r) * TT +
                       tloc + 32 * mh + 16 * mt + l15] = f2bf(a[r]);
            }
        }
    }
}

// ---------------------------------------------------------------------------
// Kernel 2a: attention partials, LDS-STAGED K/V (fixes the scattered-load
// TA serialization that made R1-R9 attn latency-bound). 320 blocks x 4 waves.
// Per 64-key chunk: block cooperatively stages K tile [64kv][64h] and V^T
// tile [64h][64kv] (8KB each) via global_load_lds w16, double-buffered,
// 1 syncthreads/chunk. XOR swizzle (16B-unit ^ row&7) applied BOTH sides:
// pre-swizzled global source + swizzled LDS read (rule #21). Wave w owns
// q-rows [64j+16w,+16); fragments read from LDS; softmax in registers.
// j<8 (single-segment) blocks write d_out directly.
// ---------------------------------------------------------------------------
__global__ __launch_bounds__(256, 2) void attn_partial_kernel(
    const unsigned short* __restrict__ qw,
    const unsigned short* __restrict__ kw,
    const unsigned short* __restrict__ vw,
    float* __restrict__ om_ws, float* __restrict__ ol_ws,
    float* __restrict__ oo_ws, float* __restrict__ out)
{
    __shared__ __align__(16) unsigned short kbuf[2][4096];  // 2 x 8KB
    __shared__ __align__(16) unsigned short vbuf[2][4096];  // 2 x 8KB

    const int s = blockIdx.x;
    const int b = s & 3;
    const int t = 79 - (s >> 2);                  // heavy segments first
    int j, seg;
    if (t < 8)       { j = t;                   seg = 0; }
    else if (t < 24) { j = 8 + ((t - 8) >> 1);  seg = (t - 8) & 1; }
    else if (t < 48) { j = 16 + (t - 24) / 3;   seg = (t - 24) % 3; }
    else             { j = 24 + ((t - 48) >> 2); seg = (t - 48) & 3; }

    const int tid = threadIdx.x;
    const int w = tid >> 6;
    const int lane = tid & 63;
    const int l15 = lane & 15, g = lane >> 4;
    const int q0w = 64 * j + 16 * w;
    const int q = q0w + l15;

    const unsigned short* qrow = qw + (size_t)(b * TT + q) * HH + 8 * g;
    ushort8 qf0 = *(const ushort8*)qrow;
    ushort8 qf1 = *(const ushort8*)(qrow + 32);

    const unsigned short* kb = kw + (size_t)b * TT * HH;
    const unsigned short* vb = vw + (size_t)b * HH * TT;

    const int kstart = 512 * seg;
    const int kend_b = min(kstart + 512, 64 * j + 64);   // block chunk range
    const int kend_w = min(kend_b, q0w + 16);            // this wave's range
    const int nchunks = (kend_b - kstart + 63) >> 6;

    // staging decode: wave w stages K rows / V h-rows [16w, 16w+16)
    const int srow_lo = 16 * w + (lane >> 3);            // rows 16w..16w+7
    const int ss = lane & 7;
    const int swz_lo = (ss ^ (srow_lo & 7)) << 3;        // pre-swizzled unit
    const int srow_hi = srow_lo + 8;
    const int swz_hi = (ss ^ (srow_hi & 7)) << 3;

#define STAGE_KV(bf, kv)                                                     \
    do {                                                                     \
        GLDS16(kb + (size_t)((kv) + srow_lo) * HH + swz_lo,                  \
               &kbuf[bf][(16 * w) * 64]);                                    \
        GLDS16(kb + (size_t)((kv) + srow_hi) * HH + swz_hi,                  \
               &kbuf[bf][(16 * w + 8) * 64]);                                \
        GLDS16(vb + (size_t)srow_lo * TT + (kv) + swz_lo,                    \
               &vbuf[bf][(16 * w) * 64]);                                    \
        GLDS16(vb + (size_t)srow_hi * TT + (kv) + swz_hi,                    \
               &vbuf[bf][(16 * w + 8) * 64]);                                \
    } while (0)

    float m_run = -3.0e38f, l_run = 0.0f;
    float4v o[4];
#pragma unroll
    for (int i = 0; i < 4; ++i) o[i] = (float4v)0.0f;

    STAGE_KV(0, kstart);
    __syncthreads();

    for (int ic = 0; ic < nchunks; ++ic) {
        const int kv0 = kstart + 64 * ic;
        const int cur = ic & 1;
        if (ic + 1 < nchunks) STAGE_KV(cur ^ 1, kv0 + 64);

        if (kv0 < kend_w) {
            const unsigned short* ks = kbuf[cur];
            const unsigned short* vs = vbuf[cur];

            ushort8 akl[4], akh[4];
#pragma unroll
            for (int f = 0; f < 4; ++f) {
                const int row = 16 * f + l15, r7 = row & 7;
                akl[f] = *(const ushort8*)&ks[row * 64 + ((g ^ r7) << 3)];
                akh[f] = *(const ushort8*)&ks[row * 64 + (((4 + g) ^ r7) << 3)];
            }
            ushort8 av[4][2];
#pragma unroll
            for (int ht = 0; ht < 4; ++ht) {
                const int hrow = 16 * ht + l15, hr7 = hrow & 7;
                const int hb = hrow * 64, lo = (g & 1) << 2, gh = g >> 1;
                ushort4v v0 = *(const ushort4v*)&vs[hb + ((gh ^ hr7) << 3) + lo];
                ushort4v v1 = *(const ushort4v*)&vs[hb + (((2 + gh) ^ hr7) << 3) + lo];
                ushort4v v2 = *(const ushort4v*)&vs[hb + (((4 + gh) ^ hr7) << 3) + lo];
                ushort4v v3 = *(const ushort4v*)&vs[hb + (((6 + gh) ^ hr7) << 3) + lo];
#pragma unroll
                for (int r = 0; r < 4; ++r) {
                    av[ht][0][r] = v0[r]; av[ht][0][4 + r] = v1[r];
                    av[ht][1][r] = v2[r]; av[ht][1][4 + r] = v3[r];
                }
            }

            float4v sc[4];                        // S^T: lane=q, key=16f+4g+r
#pragma unroll
            for (int f = 0; f < 4; ++f) {
                sc[f] = mfma16(akl[f], qf0, (float4v)0.0f);
                sc[f] = mfma16(akh[f], qf1, sc[f]);
            }

            if (kv0 + 63 > q0w) {                 // causal mask near diagonal
#pragma unroll
                for (int f = 0; f < 4; ++f)
#pragma unroll
                    for (int r = 0; r < 4; ++r)
                        if (kv0 + 16 * f + 4 * g + r > q) sc[f][r] = -1e30f;
            }

            float mt = sc[0][0];
#pragma unroll
            for (int f = 0; f < 4; ++f)
#pragma unroll
                for (int r = 0; r < 4; ++r) mt = fmaxf(mt, sc[f][r]);
            mt = fmaxf(mt, __shfl_xor(mt, 16, 64));
            mt = fmaxf(mt, __shfl_xor(mt, 32, 64));

            const float m_new = fmaxf(m_run, mt);
            const float scale = exp2f(m_run - m_new);
            float sum = 0.0f;
#pragma unroll
            for (int f = 0; f < 4; ++f)
#pragma unroll
                for (int r = 0; r < 4; ++r) {
                    sc[f][r] = exp2f(sc[f][r] - m_new);
                    sum += sc[f][r];
                }
            l_run = l_run * scale + sum;
            m_run = m_new;
#pragma unroll
            for (int i = 0; i < 4; ++i) o[i] *= scale;

            ushort8 bp[2];                        // kappa-packed P
#pragma unroll
            for (int r = 0; r < 4; ++r) {
                bp[0][r] = f2bf(sc[0][r]); bp[0][4 + r] = f2bf(sc[1][r]);
                bp[1][r] = f2bf(sc[2][r]); bp[1][4 + r] = f2bf(sc[3][r]);
            }
#pragma unroll
            for (int ht = 0; ht < 4; ++ht) {
                o[ht] = mfma16(av[ht][0], bp[0], o[ht]);
                o[ht] = mfma16(av[ht][1], bp[1], o[ht]);
            }
        }
        __syncthreads();
    }

    l_run += __shfl_xor(l_run, 16, 64);           // finish l across g-groups
    l_run += __shfl_xor(l_run, 32, 64);

    if (j < 8) {                                  // single segment: direct out
        const float inv = 1.0f / l_run;
        float* op = out + ((size_t)b * TT + q) * HH + 4 * g;
#pragma unroll
        for (int ht = 0; ht < 4; ++ht)
            *(float4v*)(op + 16 * ht) = o[ht] * inv;
    } else {
        const size_t p = (size_t)(b * 32 + j) * 4 + seg;
        if (lane < 16) {
            om_ws[p * 64 + 16 * w + l15] = m_run;
            ol_ws[p * 64 + 16 * w + l15] = l_run;
        }
#pragma unroll
        for (int ht = 0; ht < 4; ++ht)
            *(float4v*)&oo_ws[(p * 64 + 16 * w + l15) * 64 + 16 * ht + 4 * g] =
                o[ht];
    }
#undef STAGE_KV
}

// ---------------------------------------------------------------------------
// Kernel 2b: merge segment partials for tiles j>=8. 96 blocks.
// ---------------------------------------------------------------------------
__global__ __launch_bounds__(256) void attn_merge_kernel(
    const float* __restrict__ om_ws, const float* __restrict__ ol_ws,
    const float* __restrict__ oo_ws, float* __restrict__ out)
{
    const int b = blockIdx.x & 3, j = 8 + (blockIdx.x >> 2);
    const int nseg = (j >> 3) + 1;
    const size_t base = (size_t)(b * 32 + j) * 4;
    const int tid = threadIdx.x;
#pragma unroll 4
    for (int k = 0; k < 16; ++k) {
        const int e = tid + 256 * k;
        const int row = e >> 6, h = e & 63;
        float mstar = -3.0e38f;
        for (int p2 = 0; p2 < nseg; ++p2)
            mstar = fmaxf(mstar, om_ws[(base + p2) * 64 + row]);
        float lsum = 0.0f, osum = 0.0f;
        for (int p2 = 0; p2 < nseg; ++p2) {
            const float al = exp2f(om_ws[(base + p2) * 64 + row] - mstar);
            lsum += al * ol_ws[(base + p2) * 64 + row];
            osum += al * oo_ws[((base + p2) * 64 + row) * 64 + h];
        }
        out[((size_t)b * TT + 64 * j + row) * HH + h] = osum / lsum;
    }
}

extern "C" void kernel_launch(void* const* d_in, const int* in_sizes, int n_in,
                              void* d_out, int out_size, void* d_ws, size_t ws_size,
                              hipStream_t stream) {
    // setup_inputs order: x, Wk, Wq, Wv
    const float* x  = (const float*)d_in[0];
    const float* Wk = (const float*)d_in[1];
    const float* Wq = (const float*)d_in[2];
    const float* Wv = (const float*)d_in[3];

    // ws: q|k|vT bf16 (3 x 1MB) | wf 384KB | om,ol (2 x 128KB f32) | oo 8.4MB
    unsigned short* q_ws  = (unsigned short*)d_ws;
    unsigned short* k_ws  = q_ws + (size_t)BB * TT * HH;
    unsigned short* vt_ws = k_ws + (size_t)BB * TT * HH;
    unsigned short* wf_ws = vt_ws + (size_t)BB * TT * HH;
    float* om_ws = (float*)(wf_ws + 196608);
    float* ol_ws = om_ws + 512 * 64;
    float* oo_ws = ol_ws + 512 * 64;

    wconv_kernel<<<96, 256, 0, stream>>>(Wq, Wk, Wv, wf_ws);
    proj_kernel<<<BB * TT / 64, 512, 0, stream>>>(x, wf_ws, q_ws, k_ws, vt_ws);
    attn_partial_kernel<<<320, 256, 0, stream>>>(q_ws, k_ws, vt_ws,
                                                 om_ws, ol_ws, oo_ws,
                                                 (float*)d_out);
    attn_merge_kernel<<<96, 256, 0, stream>>>(om_ws, ol_ws, oo_ws,
                                              (float*)d_out);
}

// Round 11
// 63.247 us; speedup vs baseline: 1.4871x; 1.0038x over previous
//
#include <hip/hip_runtime.h>
#include <hip/hip_bf16.h>

#define BB 4
#define TT 2048
#define CC 1024
#define HH 64
#define LOG2E 1.4426950408889634f
#define QSCALE (0.125f * LOG2E)

typedef __attribute__((ext_vector_type(8))) unsigned short ushort8;
typedef __attribute__((ext_vector_type(4))) unsigned short ushort4v;
typedef __attribute__((ext_vector_type(8))) __bf16 bf16x8;
typedef __attribute__((ext_vector_type(4))) float float4v;

static __device__ __forceinline__ unsigned short f2bf(float f) {
    return __builtin_bit_cast(unsigned short, (__bf16)f);  // RNE, hw cvt
}

static __device__ __forceinline__ float4v mfma16(ushort8 a, ushort8 b, float4v c) {
    return __builtin_amdgcn_mfma_f32_16x16x32_bf16(
        __builtin_bit_cast(bf16x8, a), __builtin_bit_cast(bf16x8, b), c, 0, 0, 0);
}

static __device__ __forceinline__ ushort8 cvt8(float4v a, float4v b) {
    ushort8 r;
#pragma unroll
    for (int i = 0; i < 4; ++i) { r[i] = f2bf(a[i]); r[4 + i] = f2bf(b[i]); }
    return r;
}

#define GLDS16(gp, lp)                                                        \
    __builtin_amdgcn_global_load_lds(                                         \
        (const __attribute__((address_space(1))) unsigned int*)(gp),          \
        (__attribute__((address_space(3))) unsigned int*)(lp), 16, 0, 0)

// raw barrier publishing LDS writes (lgkmcnt) WITHOUT draining vmcnt.
#define BARRIER()                                            \
    do {                                                     \
        asm volatile("s_waitcnt lgkmcnt(0)" ::: "memory");   \
        __builtin_amdgcn_s_barrier();                        \
        asm volatile("" ::: "memory");                       \
    } while (0)

// plain barrier with compiler-reorder fences only (no waitcnt).
#define BAR()                                                \
    do {                                                     \
        asm volatile("" ::: "memory");                       \
        __builtin_amdgcn_s_barrier();                        \
        asm volatile("" ::: "memory");                       \
    } while (0)

// ---------------------------------------------------------------------------
// Kernel 0: pack W (f32 [C][64] x3) into MFMA-B-fragment-interleaved bf16.
// unit U = ((kc*2 + ks)*12 + nt)*64 + lane, 8 bf16/unit. QSCALE folded in Wq.
// ---------------------------------------------------------------------------
__global__ __launch_bounds__(256) void wconv_kernel(
    const float* __restrict__ Wq, const float* __restrict__ Wk,
    const float* __restrict__ Wv, unsigned short* __restrict__ wf)
{
    __shared__ __align__(16) float wsT[3][64][68];   // transposed, pad 64->68
    const int kc = blockIdx.x / 6, part = blockIdx.x % 6;
    const int t = threadIdx.x;
    const int r = t >> 2, c0 = (t & 3) << 4;
    const float* Ws[3] = {Wq, Wk, Wv};
#pragma unroll
    for (int y = 0; y < 3; ++y) {
        const float* src = Ws[y] + (size_t)(kc * 64 + r) * HH + c0;
        const float sc = (y == 0) ? QSCALE : 1.0f;
#pragma unroll
        for (int i = 0; i < 16; ++i) wsT[y][c0 + i][r] = src[i] * sc;
    }
    __syncthreads();
    const int U = part * 256 + t;
    const int lane = U & 63, qq = U >> 6;
    const int nt = qq % 12, ks = qq / 12;
    const int y = nt >> 2;
    const int col = 16 * (nt & 3) + (lane & 15);
    const int kl = ks * 32 + 8 * (lane >> 4);
    float4v v0 = *(const float4v*)&wsT[y][col][kl];
    float4v v1 = *(const float4v*)&wsT[y][col][kl + 4];
    *(ushort8*)&wf[((size_t)kc * 1536 + U) * 8] = cvt8(v0, v1);
}

// ---------------------------------------------------------------------------
// Kernel 1: fused q/k/v projection -- REVERTED to the R7 configuration
// (measured-best by subtraction: ~18us). 512 blocks x 6 waves, BM=16, BK=64.
// W streamed 2-deep from frag-packed wf; x staged via 4-deep register
// pipeline into swizzled LDS; raw lgkm-only barriers, 1/step.
// v waves swap MFMA operands to emit vT[b][h][t] directly.
// ---------------------------------------------------------------------------
__global__ __launch_bounds__(384) void proj_kernel(
    const float* __restrict__ x, const unsigned short* __restrict__ wf,
    unsigned short* __restrict__ qo, unsigned short* __restrict__ ko,
    unsigned short* __restrict__ vo)
{
    __shared__ __align__(16) unsigned short xa[2][1024];   // 2 x 2KB, 16B units

    const int t0 = blockIdx.x << 4;                        // 16 rows
    const int tid = threadIdx.x;
    const int w = tid >> 6;                                // 0..5
    const int lane = tid & 63;
    const int l15 = lane & 15, g = lane >> 4;
    const int nt0 = 2 * w;                                 // tiles {nt0, nt0+1}

    // x staging (threads 0..127): 8 f32 -> one swizzled 16B LDS unit
    const bool stg = tid < 128;
    const int sr = tid >> 3, su = tid & 7;
    const int soff = (sr * 8 + (su ^ (sr & 7))) * 8;
    const float* xp = x + (size_t)(t0 + sr) * CC + su * 8;

    float4v xr[4][2];                                      // 4-deep x pipeline
    if (stg) {
#pragma unroll
        for (int p = 0; p < 4; ++p) {
            xr[p][0] = *(const float4v*)(xp + p * 64);
            xr[p][1] = *(const float4v*)(xp + p * 64 + 4);
        }
    }

    // W stream: slot s = kc*2+ks at wp + s*6144 (+512 for second tile)
    const unsigned short* wp = wf + ((size_t)nt0 * 64 + lane) * 8;
    ushort8 bc[2][2], bn[2][2];
#pragma unroll
    for (int ks = 0; ks < 2; ++ks)
#pragma unroll
        for (int j = 0; j < 2; ++j) {
            bc[j][ks] = *(const ushort8*)(wp + (size_t)ks * 6144 + j * 512);
            bn[j][ks] = *(const ushort8*)(wp + (size_t)(2 + ks) * 6144 + j * 512);
        }

    if (stg) *(ushort8*)&xa[0][soff] = cvt8(xr[0][0], xr[0][1]);
    BARRIER();

    // swizzled A-frag read offsets
    const int sw = l15 & 7;
    const int r00 = (l15 * 8 + (g ^ sw)) * 8;
    const int r01 = (l15 * 8 + ((4 + g) ^ sw)) * 8;

    float4v acc[2];
    acc[0] = (float4v)0.0f; acc[1] = (float4v)0.0f;

#pragma unroll
    for (int kc = 0; kc < 16; ++kc) {
        const int cur = kc & 1;
        if (stg && kc + 4 < 16) {                          // issue x kc+4
            xr[kc & 3][0] = *(const float4v*)(xp + (kc + 4) * 64);
            xr[kc & 3][1] = *(const float4v*)(xp + (kc + 4) * 64 + 4);
        }
        ushort8 nw[2][2];
        if (kc + 2 < 16) {                                 // issue W kc+2
#pragma unroll
            for (int ks = 0; ks < 2; ++ks)
#pragma unroll
                for (int j = 0; j < 2; ++j)
                    nw[j][ks] = *(const ushort8*)
                        (wp + (size_t)(2 * kc + 4 + ks) * 6144 + j * 512);
        }
        ushort8 a0 = *(const ushort8*)&xa[cur][r00];
        ushort8 a1 = *(const ushort8*)&xa[cur][r01];
        if (w < 4) {                      // q,k: D = x*W   (row=t, col=h)
#pragma unroll
            for (int j = 0; j < 2; ++j) {
                acc[j] = mfma16(a0, bc[j][0], acc[j]);
                acc[j] = mfma16(a1, bc[j][1], acc[j]);
            }
        } else {                          // v: D = (x*W)^T (row=h, col=t)
#pragma unroll
            for (int j = 0; j < 2; ++j) {
                acc[j] = mfma16(bc[j][0], a0, acc[j]);
                acc[j] = mfma16(bc[j][1], a1, acc[j]);
            }
        }
        if (stg && kc + 1 < 16)                            // stage x kc+1
            *(ushort8*)&xa[cur ^ 1][soff] =
                cvt8(xr[(kc + 1) & 3][0], xr[(kc + 1) & 3][1]);
        BARRIER();
#pragma unroll
        for (int ks = 0; ks < 2; ++ks)
#pragma unroll
            for (int j = 0; j < 2; ++j) {
                bc[j][ks] = bn[j][ks];
                if (kc + 2 < 16) bn[j][ks] = nw[j][ks];
            }
    }

    if (w < 4) {
        unsigned short* dst = (w < 2) ? qo : ko;
#pragma unroll
        for (int j = 0; j < 2; ++j) {
            const int nf = (nt0 + j) & 3;
#pragma unroll
            for (int r = 0; r < 4; ++r)
                dst[(size_t)(t0 + 4 * g + r) * HH + 16 * nf + l15] =
                    f2bf(acc[j][r]);
        }
    } else {
        const int b = t0 >> 11, tl = t0 & (TT - 1);
#pragma unroll
        for (int j = 0; j < 2; ++j) {
            const int nf = nt0 + j - 8;
#pragma unroll
            for (int r = 0; r < 4; ++r)
                vo[((size_t)b * HH + 16 * nf + 4 * g + r) * TT + tl + l15] =
                    f2bf(acc[j][r]);
        }
    }
}

// ---------------------------------------------------------------------------
// Kernel 2a: attention partials, LDS-staged K/V + COUNTED-VMCNT pipeline.
// Per chunk: STAGE(next) issue; s_waitcnt vmcnt(16) (cur's 16 loads -- the
// oldest -- are retired; next's stay in flight across the barrier); barrier;
// compute(cur); barrier (protects cur from next iter's overwrite).
// Replaces __syncthreads' full vmcnt(0) drain (~300-400 cyc/chunk saved).
// ---------------------------------------------------------------------------
__global__ __launch_bounds__(256, 2) void attn_partial_kernel(
    const unsigned short* __restrict__ qw,
    const unsigned short* __restrict__ kw,
    const unsigned short* __restrict__ vw,
    float* __restrict__ om_ws, float* __restrict__ ol_ws,
    float* __restrict__ oo_ws, float* __restrict__ out)
{
    __shared__ __align__(16) unsigned short kbuf[2][4096];  // 2 x 8KB
    __shared__ __align__(16) unsigned short vbuf[2][4096];  // 2 x 8KB

    const int s = blockIdx.x;
    const int b = s & 3;
    const int t = 79 - (s >> 2);                  // heavy segments first
    int j, seg;
    if (t < 8)       { j = t;                   seg = 0; }
    else if (t < 24) { j = 8 + ((t - 8) >> 1);  seg = (t - 8) & 1; }
    else if (t < 48) { j = 16 + (t - 24) / 3;   seg = (t - 24) % 3; }
    else             { j = 24 + ((t - 48) >> 2); seg = (t - 48) & 3; }

    const int tid = threadIdx.x;
    const int w = tid >> 6;
    const int lane = tid & 63;
    const int l15 = lane & 15, g = lane >> 4;
    const int q0w = 64 * j + 16 * w;
    const int q = q0w + l15;

    const unsigned short* qrow = qw + (size_t)(b * TT + q) * HH + 8 * g;
    ushort8 qf0 = *(const ushort8*)qrow;
    ushort8 qf1 = *(const ushort8*)(qrow + 32);

    const unsigned short* kb = kw + (size_t)b * TT * HH;
    const unsigned short* vb = vw + (size_t)b * HH * TT;

    const int kstart = 512 * seg;
    const int kend_b = min(kstart + 512, 64 * j + 64);   // block chunk range
    const int kend_w = min(kend_b, q0w + 16);            // this wave's range
    const int nchunks = (kend_b - kstart + 63) >> 6;

    // staging decode: wave w stages K rows / V h-rows [16w, 16w+16)
    const int srow_lo = 16 * w + (lane >> 3);            // rows 16w..16w+7
    const int ss = lane & 7;
    const int swz_lo = (ss ^ (srow_lo & 7)) << 3;        // pre-swizzled unit
    const int srow_hi = srow_lo + 8;
    const int swz_hi = (ss ^ (srow_hi & 7)) << 3;

#define STAGE_KV(bf, kv)                                                     \
    do {                                                                     \
        GLDS16(kb + (size_t)((kv) + srow_lo) * HH + swz_lo,                  \
               &kbuf[bf][(16 * w) * 64]);                                    \
        GLDS16(kb + (size_t)((kv) + srow_hi) * HH + swz_hi,                  \
               &kbuf[bf][(16 * w + 8) * 64]);                                \
        GLDS16(vb + (size_t)srow_lo * TT + (kv) + swz_lo,                    \
               &vbuf[bf][(16 * w) * 64]);                                    \
        GLDS16(vb + (size_t)srow_hi * TT + (kv) + swz_hi,                    \
               &vbuf[bf][(16 * w + 8) * 64]);                                \
    } while (0)

    float m_run = -3.0e38f, l_run = 0.0f;
    float4v o[4];
#pragma unroll
    for (int i = 0; i < 4; ++i) o[i] = (float4v)0.0f;

    STAGE_KV(0, kstart);                          // 16 loads/wave in flight

    for (int ic = 0; ic < nchunks; ++ic) {
        const int kv0 = kstart + 64 * ic;
        const int cur = ic & 1;
        if (ic + 1 < nchunks) {
            STAGE_KV(cur ^ 1, kv0 + 64);          // +16 -> 32 outstanding
            asm volatile("s_waitcnt vmcnt(16)" ::: "memory");  // cur landed
        } else {
            asm volatile("s_waitcnt vmcnt(0)" ::: "memory");
        }
        BAR();                                    // all waves: cur ready

        if (kv0 < kend_w) {
            const unsigned short* ks = kbuf[cur];
            const unsigned short* vs = vbuf[cur];

            ushort8 akl[4], akh[4];
#pragma unroll
            for (int f = 0; f < 4; ++f) {
                const int row = 16 * f + l15, r7 = row & 7;
                akl[f] = *(const ushort8*)&ks[row * 64 + ((g ^ r7) << 3)];
                akh[f] = *(const ushort8*)&ks[row * 64 + (((4 + g) ^ r7) << 3)];
            }
            ushort8 av[4][2];
#pragma unroll
            for (int ht = 0; ht < 4; ++ht) {
                const int hrow = 16 * ht + l15, hr7 = hrow & 7;
                const int hb = hrow * 64, lo = (g & 1) << 2, gh = g >> 1;
                ushort4v v0 = *(const ushort4v*)&vs[hb + ((gh ^ hr7) << 3) + lo];
                ushort4v v1 = *(const ushort4v*)&vs[hb + (((2 + gh) ^ hr7) << 3) + lo];
                ushort4v v2 = *(const ushort4v*)&vs[hb + (((4 + gh) ^ hr7) << 3) + lo];
                ushort4v v3 = *(const ushort4v*)&vs[hb + (((6 + gh) ^ hr7) << 3) + lo];
#pragma unroll
                for (int r = 0; r < 4; ++r) {
                    av[ht][0][r] = v0[r]; av[ht][0][4 + r] = v1[r];
                    av[ht][1][r] = v2[r]; av[ht][1][4 + r] = v3[r];
                }
            }

            float4v sc[4];                        // S^T: lane=q, key=16f+4g+r
#pragma unroll
            for (int f = 0; f < 4; ++f) {
                sc[f] = mfma16(akl[f], qf0, (float4v)0.0f);
                sc[f] = mfma16(akh[f], qf1, sc[f]);
            }

            if (kv0 + 63 > q0w) {                 // causal mask near diagonal
#pragma unroll
                for (int f = 0; f < 4; ++f)
#pragma unroll
                    for (int r = 0; r < 4; ++r)
                        if (kv0 + 16 * f + 4 * g + r > q) sc[f][r] = -1e30f;
            }

            float mt = sc[0][0];
#pragma unroll
            for (int f = 0; f < 4; ++f)
#pragma unroll
                for (int r = 0; r < 4; ++r) mt = fmaxf(mt, sc[f][r]);
            mt = fmaxf(mt, __shfl_xor(mt, 16, 64));
            mt = fmaxf(mt, __shfl_xor(mt, 32, 64));

            const float m_new = fmaxf(m_run, mt);
            const float scale = exp2f(m_run - m_new);
            float sum = 0.0f;
#pragma unroll
            for (int f = 0; f < 4; ++f)
#pragma unroll
                for (int r = 0; r < 4; ++r) {
                    sc[f][r] = exp2f(sc[f][r] - m_new);
                    sum += sc[f][r];
                }
            l_run = l_run * scale + sum;
            m_run = m_new;
#pragma unroll
            for (int i = 0; i < 4; ++i) o[i] *= scale;

            ushort8 bp[2];                        // kappa-packed P
#pragma unroll
            for (int r = 0; r < 4; ++r) {
                bp[0][r] = f2bf(sc[0][r]); bp[0][4 + r] = f2bf(sc[1][r]);
                bp[1][r] = f2bf(sc[2][r]); bp[1][4 + r] = f2bf(sc[3][r]);
            }
#pragma unroll
            for (int ht = 0; ht < 4; ++ht) {
                o[ht] = mfma16(av[ht][0], bp[0], o[ht]);
                o[ht] = mfma16(av[ht][1], bp[1], o[ht]);
            }
        }
        BAR();                                    // all done reading cur
    }

    l_run += __shfl_xor(l_run, 16, 64);           // finish l across g-groups
    l_run += __shfl_xor(l_run, 32, 64);

    if (j < 8) {                                  // single segment: direct out
        const float inv = 1.0f / l_run;
        float* op = out + ((size_t)b * TT + q) * HH + 4 * g;
#pragma unroll
        for (int ht = 0; ht < 4; ++ht)
            *(float4v*)(op + 16 * ht) = o[ht] * inv;
    } else {
        const size_t p = (size_t)(b * 32 + j) * 4 + seg;
        if (lane < 16) {
            om_ws[p * 64 + 16 * w + l15] = m_run;
            ol_ws[p * 64 + 16 * w + l15] = l_run;
        }
#pragma unroll
        for (int ht = 0; ht < 4; ++ht)
            *(float4v*)&oo_ws[(p * 64 + 16 * w + l15) * 64 + 16 * ht + 4 * g] =
                o[ht];
    }
#undef STAGE_KV
}

// ---------------------------------------------------------------------------
// Kernel 2b: merge segment partials for tiles j>=8. 96 blocks.
// ---------------------------------------------------------------------------
__global__ __launch_bounds__(256) void attn_merge_kernel(
    const float* __restrict__ om_ws, const float* __restrict__ ol_ws,
    const float* __restrict__ oo_ws, float* __restrict__ out)
{
    const int b = blockIdx.x & 3, j = 8 + (blockIdx.x >> 2);
    const int nseg = (j >> 3) + 1;
    const size_t base = (size_t)(b * 32 + j) * 4;
    const int tid = threadIdx.x;
#pragma unroll 4
    for (int k = 0; k < 16; ++k) {
        const int e = tid + 256 * k;
        const int row = e >> 6, h = e & 63;
        float mstar = -3.0e38f;
        for (int p2 = 0; p2 < nseg; ++p2)
            mstar = fmaxf(mstar, om_ws[(base + p2) * 64 + row]);
        float lsum = 0.0f, osum = 0.0f;
        for (int p2 = 0; p2 < nseg; ++p2) {
            const float al = exp2f(om_ws[(base + p2) * 64 + row] - mstar);
            lsum += al * ol_ws[(base + p2) * 64 + row];
            osum += al * oo_ws[((base + p2) * 64 + row) * 64 + h];
        }
        out[((size_t)b * TT + 64 * j + row) * HH + h] = osum / lsum;
    }
}

extern "C" void kernel_launch(void* const* d_in, const int* in_sizes, int n_in,
                              void* d_out, int out_size, void* d_ws, size_t ws_size,
                              hipStream_t stream) {
    // setup_inputs order: x, Wk, Wq, Wv
    const float* x  = (const float*)d_in[0];
    const float* Wk = (const float*)d_in[1];
    const float* Wq = (const float*)d_in[2];
    const float* Wv = (const float*)d_in[3];

    // ws: q|k|vT bf16 (3 x 1MB) | wf 384KB | om,ol (2 x 128KB f32) | oo 8.4MB
    unsigned short* q_ws  = (unsigned short*)d_ws;
    unsigned short* k_ws  = q_ws + (size_t)BB * TT * HH;
    unsigned short* vt_ws = k_ws + (size_t)BB * TT * HH;
    unsigned short* wf_ws = vt_ws + (size_t)BB * TT * HH;
    float* om_ws = (float*)(wf_ws + 196608);
    float* ol_ws = om_ws + 512 * 64;
    float* oo_ws = ol_ws + 512 * 64;

    wconv_kernel<<<96, 256, 0, stream>>>(Wq, Wk, Wv, wf_ws);
    proj_kernel<<<BB * TT / 16, 384, 0, stream>>>(x, wf_ws, q_ws, k_ws, vt_ws);
    attn_partial_kernel<<<320, 256, 0, stream>>>(q_ws, k_ws, vt_ws,
                                                 om_ws, ol_ws, oo_ws,
                                                 (float*)d_out);
    attn_merge_kernel<<<96, 256, 0, stream>>>(om_ws, ol_ws, oo_ws,
                                              (float*)d_out);
}

// Round 12
// 62.676 us; speedup vs baseline: 1.5006x; 1.0091x over previous
//
#include <hip/hip_runtime.h>
#include <hip/hip_bf16.h>

#define BB 4
#define TT 2048
#define CC 1024
#define HH 64
#define LOG2E 1.4426950408889634f
#define QSCALE (0.125f * LOG2E)

typedef __attribute__((ext_vector_type(8))) unsigned short ushort8;
typedef __attribute__((ext_vector_type(4))) unsigned short ushort4v;
typedef __attribute__((ext_vector_type(8))) __bf16 bf16x8;
typedef __attribute__((ext_vector_type(4))) float float4v;

static __device__ __forceinline__ unsigned short f2bf(float f) {
    return __builtin_bit_cast(unsigned short, (__bf16)f);  // RNE, hw cvt
}

static __device__ __forceinline__ float4v mfma16(ushort8 a, ushort8 b, float4v c) {
    return __builtin_amdgcn_mfma_f32_16x16x32_bf16(
        __builtin_bit_cast(bf16x8, a), __builtin_bit_cast(bf16x8, b), c, 0, 0, 0);
}

static __device__ __forceinline__ ushort8 cvt8(float4v a, float4v b) {
    ushort8 r;
#pragma unroll
    for (int i = 0; i < 4; ++i) { r[i] = f2bf(a[i]); r[4 + i] = f2bf(b[i]); }
    return r;
}

#define GLDS16(gp, lp)                                                        \
    __builtin_amdgcn_global_load_lds(                                         \
        (const __attribute__((address_space(1))) unsigned int*)(gp),          \
        (__attribute__((address_space(3))) unsigned int*)(lp), 16, 0, 0)

// raw barrier publishing LDS writes (lgkmcnt) WITHOUT draining vmcnt —
// used in proj where prefetches must stay in flight across steps.
#define BARRIER()                                            \
    do {                                                     \
        asm volatile("s_waitcnt lgkmcnt(0)" ::: "memory");   \
        __builtin_amdgcn_s_barrier();                        \
        asm volatile("" ::: "memory");                       \
    } while (0)

// ---------------------------------------------------------------------------
// Kernel 0: pack W (f32 [C][64] x3) into MFMA-B-fragment-interleaved bf16.
// unit U = ((kc*2 + ks)*12 + nt)*64 + lane, 8 bf16/unit. QSCALE folded in Wq.
// ---------------------------------------------------------------------------
__global__ __launch_bounds__(256) void wconv_kernel(
    const float* __restrict__ Wq, const float* __restrict__ Wk,
    const float* __restrict__ Wv, unsigned short* __restrict__ wf)
{
    __shared__ __align__(16) float wsT[3][64][68];   // transposed, pad 64->68
    const int kc = blockIdx.x / 6, part = blockIdx.x % 6;
    const int t = threadIdx.x;
    const int r = t >> 2, c0 = (t & 3) << 4;
    const float* Ws[3] = {Wq, Wk, Wv};
#pragma unroll
    for (int y = 0; y < 3; ++y) {
        const float* src = Ws[y] + (size_t)(kc * 64 + r) * HH + c0;
        const float sc = (y == 0) ? QSCALE : 1.0f;
#pragma unroll
        for (int i = 0; i < 16; ++i) wsT[y][c0 + i][r] = src[i] * sc;
    }
    __syncthreads();
    const int U = part * 256 + t;
    const int lane = U & 63, qq = U >> 6;
    const int nt = qq % 12, ks = qq / 12;
    const int y = nt >> 2;
    const int col = 16 * (nt & 3) + (lane & 15);
    const int kl = ks * 32 + 8 * (lane >> 4);
    float4v v0 = *(const float4v*)&wsT[y][col][kl];
    float4v v1 = *(const float4v*)&wsT[y][col][kl + 4];
    *(ushort8*)&wf[((size_t)kc * 1536 + U) * 8] = cvt8(v0, v1);
}

// ---------------------------------------------------------------------------
// Kernel 1: fused q/k/v projection (R7 config, measured-best ~18us).
// 512 blocks x 6 waves, BM=16, BK=64. W streamed 2-deep from frag-packed wf;
// x staged via 4-deep register pipeline into swizzled LDS; raw lgkm-only
// barriers, 1/step. v waves swap MFMA operands to emit vT[b][h][t].
// ---------------------------------------------------------------------------
__global__ __launch_bounds__(384) void proj_kernel(
    const float* __restrict__ x, const unsigned short* __restrict__ wf,
    unsigned short* __restrict__ qo, unsigned short* __restrict__ ko,
    unsigned short* __restrict__ vo)
{
    __shared__ __align__(16) unsigned short xa[2][1024];   // 2 x 2KB, 16B units

    const int t0 = blockIdx.x << 4;                        // 16 rows
    const int tid = threadIdx.x;
    const int w = tid >> 6;                                // 0..5
    const int lane = tid & 63;
    const int l15 = lane & 15, g = lane >> 4;
    const int nt0 = 2 * w;                                 // tiles {nt0, nt0+1}

    // x staging (threads 0..127): 8 f32 -> one swizzled 16B LDS unit
    const bool stg = tid < 128;
    const int sr = tid >> 3, su = tid & 7;
    const int soff = (sr * 8 + (su ^ (sr & 7))) * 8;
    const float* xp = x + (size_t)(t0 + sr) * CC + su * 8;

    float4v xr[4][2];                                      // 4-deep x pipeline
    if (stg) {
#pragma unroll
        for (int p = 0; p < 4; ++p) {
            xr[p][0] = *(const float4v*)(xp + p * 64);
            xr[p][1] = *(const float4v*)(xp + p * 64 + 4);
        }
    }

    // W stream: slot s = kc*2+ks at wp + s*6144 (+512 for second tile)
    const unsigned short* wp = wf + ((size_t)nt0 * 64 + lane) * 8;
    ushort8 bc[2][2], bn[2][2];
#pragma unroll
    for (int ks = 0; ks < 2; ++ks)
#pragma unroll
        for (int j = 0; j < 2; ++j) {
            bc[j][ks] = *(const ushort8*)(wp + (size_t)ks * 6144 + j * 512);
            bn[j][ks] = *(const ushort8*)(wp + (size_t)(2 + ks) * 6144 + j * 512);
        }

    if (stg) *(ushort8*)&xa[0][soff] = cvt8(xr[0][0], xr[0][1]);
    BARRIER();

    // swizzled A-frag read offsets
    const int sw = l15 & 7;
    const int r00 = (l15 * 8 + (g ^ sw)) * 8;
    const int r01 = (l15 * 8 + ((4 + g) ^ sw)) * 8;

    float4v acc[2];
    acc[0] = (float4v)0.0f; acc[1] = (float4v)0.0f;

#pragma unroll
    for (int kc = 0; kc < 16; ++kc) {
        const int cur = kc & 1;
        if (stg && kc + 4 < 16) {                          // issue x kc+4
            xr[kc & 3][0] = *(const float4v*)(xp + (kc + 4) * 64);
            xr[kc & 3][1] = *(const float4v*)(xp + (kc + 4) * 64 + 4);
        }
        ushort8 nw[2][2];
        if (kc + 2 < 16) {                                 // issue W kc+2
#pragma unroll
            for (int ks = 0; ks < 2; ++ks)
#pragma unroll
                for (int j = 0; j < 2; ++j)
                    nw[j][ks] = *(const ushort8*)
                        (wp + (size_t)(2 * kc + 4 + ks) * 6144 + j * 512);
        }
        ushort8 a0 = *(const ushort8*)&xa[cur][r00];
        ushort8 a1 = *(const ushort8*)&xa[cur][r01];
        if (w < 4) {                      // q,k: D = x*W   (row=t, col=h)
#pragma unroll
            for (int j = 0; j < 2; ++j) {
                acc[j] = mfma16(a0, bc[j][0], acc[j]);
                acc[j] = mfma16(a1, bc[j][1], acc[j]);
            }
        } else {                          // v: D = (x*W)^T (row=h, col=t)
#pragma unroll
            for (int j = 0; j < 2; ++j) {
                acc[j] = mfma16(bc[j][0], a0, acc[j]);
                acc[j] = mfma16(bc[j][1], a1, acc[j]);
            }
        }
        if (stg && kc + 1 < 16)                            // stage x kc+1
            *(ushort8*)&xa[cur ^ 1][soff] =
                cvt8(xr[(kc + 1) & 3][0], xr[(kc + 1) & 3][1]);
        BARRIER();
#pragma unroll
        for (int ks = 0; ks < 2; ++ks)
#pragma unroll
            for (int j = 0; j < 2; ++j) {
                bc[j][ks] = bn[j][ks];
                if (kc + 2 < 16) bn[j][ks] = nw[j][ks];
            }
    }

    if (w < 4) {
        unsigned short* dst = (w < 2) ? qo : ko;
#pragma unroll
        for (int j = 0; j < 2; ++j) {
            const int nf = (nt0 + j) & 3;
#pragma unroll
            for (int r = 0; r < 4; ++r)
                dst[(size_t)(t0 + 4 * g + r) * HH + 16 * nf + l15] =
                    f2bf(acc[j][r]);
        }
    } else {
        const int b = t0 >> 11, tl = t0 & (TT - 1);
#pragma unroll
        for (int j = 0; j < 2; ++j) {
            const int nf = nt0 + j - 8;
#pragma unroll
            for (int r = 0; r < 4; ++r)
                vo[((size_t)b * HH + 16 * nf + 4 * g + r) * TT + tl + l15] =
                    f2bf(acc[j][r]);
        }
    }
}

// ---------------------------------------------------------------------------
// Kernel 2a: attention partials, LDS-staged K/V -- REVERTED to the R10
// __syncthreads() pipeline (measured ~15.5us by R9/R10 subtraction; R11's
// counted-vmcnt variant coincided with a large regression AND carried a
// vmcnt(16) no-op race -- abandoned). STAGE(next) issued before compute(cur);
// __syncthreads drains vmcnt(0) after compute, so next's loads had the whole
// compute phase to land. 320 blocks x 4 waves, heavy-first decode.
// ---------------------------------------------------------------------------
__global__ __launch_bounds__(256, 2) void attn_partial_kernel(
    const unsigned short* __restrict__ qw,
    const unsigned short* __restrict__ kw,
    const unsigned short* __restrict__ vw,
    float* __restrict__ om_ws, float* __restrict__ ol_ws,
    float* __restrict__ oo_ws, float* __restrict__ out)
{
    __shared__ __align__(16) unsigned short kbuf[2][4096];  // 2 x 8KB
    __shared__ __align__(16) unsigned short vbuf[2][4096];  // 2 x 8KB

    const int s = blockIdx.x;
    const int b = s & 3;
    const int t = 79 - (s >> 2);                  // heavy segments first
    int j, seg;
    if (t < 8)       { j = t;                   seg = 0; }
    else if (t < 24) { j = 8 + ((t - 8) >> 1);  seg = (t - 8) & 1; }
    else if (t < 48) { j = 16 + (t - 24) / 3;   seg = (t - 24) % 3; }
    else             { j = 24 + ((t - 48) >> 2); seg = (t - 48) & 3; }

    const int tid = threadIdx.x;
    const int w = tid >> 6;
    const int lane = tid & 63;
    const int l15 = lane & 15, g = lane >> 4;
    const int q0w = 64 * j + 16 * w;
    const int q = q0w + l15;

    const unsigned short* qrow = qw + (size_t)(b * TT + q) * HH + 8 * g;
    ushort8 qf0 = *(const ushort8*)qrow;
    ushort8 qf1 = *(const ushort8*)(qrow + 32);

    const unsigned short* kb = kw + (size_t)b * TT * HH;
    const unsigned short* vb = vw + (size_t)b * HH * TT;

    const int kstart = 512 * seg;
    const int kend_b = min(kstart + 512, 64 * j + 64);   // block chunk range
    const int kend_w = min(kend_b, q0w + 16);            // this wave's range
    const int nchunks = (kend_b - kstart + 63) >> 6;

    // staging decode: wave w stages K rows / V h-rows [16w, 16w+16)
    const int srow_lo = 16 * w + (lane >> 3);            // rows 16w..16w+7
    const int ss = lane & 7;
    const int swz_lo = (ss ^ (srow_lo & 7)) << 3;        // pre-swizzled unit
    const int srow_hi = srow_lo + 8;
    const int swz_hi = (ss ^ (srow_hi & 7)) << 3;

#define STAGE_KV(bf, kv)                                                     \
    do {                                                                     \
        GLDS16(kb + (size_t)((kv) + srow_lo) * HH + swz_lo,                  \
               &kbuf[bf][(16 * w) * 64]);                                    \
        GLDS16(kb + (size_t)((kv) + srow_hi) * HH + swz_hi,                  \
               &kbuf[bf][(16 * w + 8) * 64]);                                \
        GLDS16(vb + (size_t)srow_lo * TT + (kv) + swz_lo,                    \
               &vbuf[bf][(16 * w) * 64]);                                    \
        GLDS16(vb + (size_t)srow_hi * TT + (kv) + swz_hi,                    \
               &vbuf[bf][(16 * w + 8) * 64]);                                \
    } while (0)

    float m_run = -3.0e38f, l_run = 0.0f;
    float4v o[4];
#pragma unroll
    for (int i = 0; i < 4; ++i) o[i] = (float4v)0.0f;

    STAGE_KV(0, kstart);
    __syncthreads();

    for (int ic = 0; ic < nchunks; ++ic) {
        const int kv0 = kstart + 64 * ic;
        const int cur = ic & 1;
        if (ic + 1 < nchunks) STAGE_KV(cur ^ 1, kv0 + 64);

        if (kv0 < kend_w) {
            const unsigned short* ks = kbuf[cur];
            const unsigned short* vs = vbuf[cur];

            ushort8 akl[4], akh[4];
#pragma unroll
            for (int f = 0; f < 4; ++f) {
                const int row = 16 * f + l15, r7 = row & 7;
                akl[f] = *(const ushort8*)&ks[row * 64 + ((g ^ r7) << 3)];
                akh[f] = *(const ushort8*)&ks[row * 64 + (((4 + g) ^ r7) << 3)];
            }
            ushort8 av[4][2];
#pragma unroll
            for (int ht = 0; ht < 4; ++ht) {
                const int hrow = 16 * ht + l15, hr7 = hrow & 7;
                const int hb = hrow * 64, lo = (g & 1) << 2, gh = g >> 1;
                ushort4v v0 = *(const ushort4v*)&vs[hb + ((gh ^ hr7) << 3) + lo];
                ushort4v v1 = *(const ushort4v*)&vs[hb + (((2 + gh) ^ hr7) << 3) + lo];
                ushort4v v2 = *(const ushort4v*)&vs[hb + (((4 + gh) ^ hr7) << 3) + lo];
                ushort4v v3 = *(const ushort4v*)&vs[hb + (((6 + gh) ^ hr7) << 3) + lo];
#pragma unroll
                for (int r = 0; r < 4; ++r) {
                    av[ht][0][r] = v0[r]; av[ht][0][4 + r] = v1[r];
                    av[ht][1][r] = v2[r]; av[ht][1][4 + r] = v3[r];
                }
            }

            float4v sc[4];                        // S^T: lane=q, key=16f+4g+r
#pragma unroll
            for (int f = 0; f < 4; ++f) {
                sc[f] = mfma16(akl[f], qf0, (float4v)0.0f);
                sc[f] = mfma16(akh[f], qf1, sc[f]);
            }

            if (kv0 + 63 > q0w) {                 // causal mask near diagonal
#pragma unroll
                for (int f = 0; f < 4; ++f)
#pragma unroll
                    for (int r = 0; r < 4; ++r)
                        if (kv0 + 16 * f + 4 * g + r > q) sc[f][r] = -1e30f;
            }

            float mt = sc[0][0];
#pragma unroll
            for (int f = 0; f < 4; ++f)
#pragma unroll
                for (int r = 0; r < 4; ++r) mt = fmaxf(mt, sc[f][r]);
            mt = fmaxf(mt, __shfl_xor(mt, 16, 64));
            mt = fmaxf(mt, __shfl_xor(mt, 32, 64));

            const float m_new = fmaxf(m_run, mt);
            const float scale = exp2f(m_run - m_new);
            float sum = 0.0f;
#pragma unroll
            for (int f = 0; f < 4; ++f)
#pragma unroll
                for (int r = 0; r < 4; ++r) {
                    sc[f][r] = exp2f(sc[f][r] - m_new);
                    sum += sc[f][r];
                }
            l_run = l_run * scale + sum;
            m_run = m_new;
#pragma unroll
            for (int i = 0; i < 4; ++i) o[i] *= scale;

            ushort8 bp[2];                        // kappa-packed P
#pragma unroll
            for (int r = 0; r < 4; ++r) {
                bp[0][r] = f2bf(sc[0][r]); bp[0][4 + r] = f2bf(sc[1][r]);
                bp[1][r] = f2bf(sc[2][r]); bp[1][4 + r] = f2bf(sc[3][r]);
            }
#pragma unroll
            for (int ht = 0; ht < 4; ++ht) {
                o[ht] = mfma16(av[ht][0], bp[0], o[ht]);
                o[ht] = mfma16(av[ht][1], bp[1], o[ht]);
            }
        }
        __syncthreads();
    }

    l_run += __shfl_xor(l_run, 16, 64);           // finish l across g-groups
    l_run += __shfl_xor(l_run, 32, 64);

    if (j < 8) {                                  // single segment: direct out
        const float inv = 1.0f / l_run;
        float* op = out + ((size_t)b * TT + q) * HH + 4 * g;
#pragma unroll
        for (int ht = 0; ht < 4; ++ht)
            *(float4v*)(op + 16 * ht) = o[ht] * inv;
    } else {
        const size_t p = (size_t)(b * 32 + j) * 4 + seg;
        if (lane < 16) {
            om_ws[p * 64 + 16 * w + l15] = m_run;
            ol_ws[p * 64 + 16 * w + l15] = l_run;
        }
#pragma unroll
        for (int ht = 0; ht < 4; ++ht)
            *(float4v*)&oo_ws[(p * 64 + 16 * w + l15) * 64 + 16 * ht + 4 * g] =
                o[ht];
    }
#undef STAGE_KV
}

// ---------------------------------------------------------------------------
// Kernel 2b: merge segment partials for tiles j>=8. 96 blocks.
// ---------------------------------------------------------------------------
__global__ __launch_bounds__(256) void attn_merge_kernel(
    const float* __restrict__ om_ws, const float* __restrict__ ol_ws,
    const float* __restrict__ oo_ws, float* __restrict__ out)
{
    const int b = blockIdx.x & 3, j = 8 + (blockIdx.x >> 2);
    const int nseg = (j >> 3) + 1;
    const size_t base = (size_t)(b * 32 + j) * 4;
    const int tid = threadIdx.x;
#pragma unroll 4
    for (int k = 0; k < 16; ++k) {
        const int e = tid + 256 * k;
        const int row = e >> 6, h = e & 63;
        float mstar = -3.0e38f;
        for (int p2 = 0; p2 < nseg; ++p2)
            mstar = fmaxf(mstar, om_ws[(base + p2) * 64 + row]);
        float lsum = 0.0f, osum = 0.0f;
        for (int p2 = 0; p2 < nseg; ++p2) {
            const float al = exp2f(om_ws[(base + p2) * 64 + row] - mstar);
            lsum += al * ol_ws[(base + p2) * 64 + row];
            osum += al * oo_ws[((base + p2) * 64 + row) * 64 + h];
        }
        out[((size_t)b * TT + 64 * j + row) * HH + h] = osum / lsum;
    }
}

extern "C" void kernel_launch(void* const* d_in, const int* in_sizes, int n_in,
                              void* d_out, int out_size, void* d_ws, size_t ws_size,
                              hipStream_t stream) {
    // setup_inputs order: x, Wk, Wq, Wv
    const float* x  = (const float*)d_in[0];
    const float* Wk = (const float*)d_in[1];
    const float* Wq = (const float*)d_in[2];
    const float* Wv = (const float*)d_in[3];

    // ws: q|k|vT bf16 (3 x 1MB) | wf 384KB | om,ol (2 x 128KB f32) | oo 8.4MB
    unsigned short* q_ws  = (unsigned short*)d_ws;
    unsigned short* k_ws  = q_ws + (size_t)BB * TT * HH;
    unsigned short* vt_ws = k_ws + (size_t)BB * TT * HH;
    unsigned short* wf_ws = vt_ws + (size_t)BB * TT * HH;
    float* om_ws = (float*)(wf_ws + 196608);
    float* ol_ws = om_ws + 512 * 64;
    float* oo_ws = ol_ws + 512 * 64;

    wconv_kernel<<<96, 256, 0, stream>>>(Wq, Wk, Wv, wf_ws);
    proj_kernel<<<BB * TT / 16, 384, 0, stream>>>(x, wf_ws, q_ws, k_ws, vt_ws);
    attn_partial_kernel<<<320, 256, 0, stream>>>(q_ws, k_ws, vt_ws,
                                                 om_ws, ol_ws, oo_ws,
                                                 (float*)d_out);
    attn_merge_kernel<<<96, 256, 0, stream>>>(om_ws, ol_ws, oo_ws,
                                              (float*)d_out);
}